// Round 5
// baseline (189.654 us; speedup 1.0000x reference)
//
#include <hip/hip_runtime.h>
#include <hip/hip_bf16.h>

// Problem constants (from reference)
#define E_EDGES 262144
#define B_SAMP  1024
#define L_SEQ   10
#define T_SEG   (B_SAMP * L_SEQ)   // 10240 segments
#define H_DIM   128
#define N_ENT_C 40000
#define N_REL_C 256

typedef __attribute__((ext_vector_type(8))) short short8;   // 8 bf16 (4 VGPRs)
typedef __attribute__((ext_vector_type(4))) float f32x4;

__device__ __forceinline__ float b2f(__hip_bfloat16 x) { return __bfloat162float(x); }
__device__ __forceinline__ unsigned short f2bu(float x) {
    return __bfloat16_as_ushort(__float2bfloat16(x));
}

// Float load with runtime-detected storage (bf16 vs float32).
__device__ __forceinline__ float loadF(const void* base, int idx, int isB16) {
    if (isB16) return b2f(((const __hip_bfloat16*)base)[idx]);
    return ((const float*)base)[idx];
}
// Integer load with runtime-detected width (int64 vs int32).
__device__ __forceinline__ int loadI(const void* base, int idx, int is64) {
    if (is64) return (int)(((const long long*)base)[idx]);
    return ((const int*)base)[idx];
}

// Per-block dtype detection (cheap, deterministic; no cross-block deps).
__device__ __forceinline__ void detect_dtypes(const void* att_raw,
                                              const void* sid_raw,
                                              int tid, int nthr,
                                              int& isB, int& i64)
{
    __shared__ int cF, cI;
    if (tid == 0) { cF = 0; cI = 0; }
    __syncthreads();
    const unsigned short* pa = (const unsigned short*)att_raw;
    int c = 0;
    for (int i = tid; i < 2048; i += nthr) if (pa[i] <= 0x3F80u) c++;
    if (c) atomicAdd(&cF, c);
    const int* ps = (const int*)sid_raw;
    c = 0;
    for (int i = tid; i < 512; i += nthr) if (ps[2 * i + 1] == 0) c++;
    if (c) atomicAdd(&cI, c);
    __syncthreads();
    isB = (cF >= 1900) ? 1 : 0;
    i64 = (cI >= 256) ? 1 : 0;
}

// ---------------------------------------------------------------------------
// K_A: all prep in one launch, blocks fully independent.
//  bid [0,256):   bf16 weight tables, n-major k-contig for MFMA B-frags.
//  bid [256,321): att piecewise tables ab3p[j][h] = packed {bf16 A3, bf16 B3}.
//  bid [321,362): segment start offsets via lower_bound on sorted seg_ids.
//  bid 362:       global scalar vectors + dtype flags.
//  bid [363,619): edge-meta pass: metaE[i] = uint2{att_f32_bits,
//                 ent u16 | rel u8<<16 | bucket u8<<24}. Moves the per-edge
//                 breakpoint binary search out of K_C and lets K_C stage one
//                 dwordx2 per edge. Blocks self-derive bpts (rank sort).
// ---------------------------------------------------------------------------
__global__ void __launch_bounds__(256)
ka_prep(const void* __restrict__ W3w, const void* __restrict__ W4w,
        const void* __restrict__ W1w, const void* __restrict__ W1b,
        const void* __restrict__ W3b, const void* __restrict__ W4b,
        const void* __restrict__ seg_ids,
        const void* __restrict__ nbr_ent, const void* __restrict__ nbr_rel,
        const void* __restrict__ att_raw, const void* __restrict__ sid_raw,
        unsigned short* __restrict__ wctEb, unsigned short* __restrict__ wctRb,
        unsigned int* __restrict__ ab3p, int* __restrict__ starts,
        uint2* __restrict__ metaE,
        float* __restrict__ W1w_f, float* __restrict__ W1b_f,
        float* __restrict__ W3b_f, float* __restrict__ W4b_f,
        int* __restrict__ flag, int* __restrict__ iflag)
{
    const int bid = blockIdx.x, tid = threadIdx.x;
    int isB, i64;
    detect_dtypes(att_raw, sid_raw, tid, 256, isB, i64);

    if (bid < 256) {
        int gid = bid * 256 + tid;
        if (gid < 32768) {
            int n = gid >> 7, k = gid & 127;
            float v = (n < 128) ? loadF(W3w, n * 384 + 128 + k, isB)
                                : loadF(W4w, (n - 128) * 256 + k, isB);
            wctEb[gid] = f2bu(v);
        } else {
            int j = gid - 32768;
            int n = j >> 7, k = j & 127;
            float v = (n < 128) ? loadF(W3w, n * 384 + 256 + k, isB)
                                : loadF(W4w, (n - 128) * 256 + 128 + k, isB);
            wctRb[j] = f2bu(v);
        }
        return;
    }

    if (bid >= 321 && bid <= 361) {
        // starts blocks: lower_bound on sorted seg_ids
        int t = (bid - 321) * 256 + tid;
        if (t <= T_SEG) {
            int lo = 0, hi = E_EDGES;
            while (lo < hi) {
                int m = (lo + hi) >> 1;
                if (loadI(seg_ids, m, i64) < t) lo = m + 1; else hi = m;
            }
            starts[t] = lo;
        }
        return;
    }

    // Remaining blocks all need the sorted breakpoints: derive locally.
    // thr_k = -b1k/w1k if in (0,1) else sentinel 2.0; rank-sort in LDS.
    __shared__ float w1s[128], b1s[128], srt[128];
    __shared__ int nInS;
    if (tid < 128) {
        float w = loadF(W1w, tid, isB);
        float b = loadF(W1b, tid, isB);
        w1s[tid] = w; b1s[tid] = b;
    }
    __syncthreads();
    if (tid < 128) {
        float w = w1s[tid], b = b1s[tid];
        float t = 2.0f;
        if (w != 0.0f) {
            float tt = -b / w;
            if (tt > 0.0f && tt < 1.0f) t = tt;
        }
        srt[tid] = t;   // temporarily unsorted
    }
    __syncthreads();
    float myt = 0.0f; int rank = 0, n = 0;
    if (tid < 128) {
        myt = srt[tid];
        for (int j = 0; j < 128; ++j) {
            float v = srt[j];
            rank += (v < myt) || (v == myt && j < tid);
            n += (v < 1.5f);
        }
    }
    __syncthreads();
    if (tid < 128) srt[rank] = myt;     // now sorted
    if (tid == 0) nInS = n;
    __syncthreads();
    const int nIn = nInS;

    if (bid == 362) {
        if (tid < 128) {
            W1w_f[tid] = w1s[tid];
            W1b_f[tid] = b1s[tid];
            W3b_f[tid] = loadF(W3b, tid, isB);
            W4b_f[tid] = loadF(W4b, tid, isB);
        }
        if (tid == 0) { *flag = isB; *iflag = i64; }
        return;
    }

    if (bid < 321) {
        // ab3 blocks: j = (bid-256)*2 + (tid>>7), h = tid&127
        const int j = (bid - 256) * 2 + (tid >> 7);
        const int h = tid & 127;
        if (j <= nIn) {
            float left  = (j == 0)   ? 0.0f : srt[j - 1];
            float right = (j == nIn) ? 1.0f : srt[j];
            float mid = 0.5f * (left + right);
            float a = 0.0f, b = 0.0f;
            for (int k = 0; k < 128; ++k) {
                if (fmaf(mid, w1s[k], b1s[k]) > 0.0f) {
                    float w3 = loadF(W3w, h * 384 + k, isB);
                    a = fmaf(w1s[k], w3, a);
                    b = fmaf(b1s[k], w3, b);
                }
            }
            ab3p[j * 128 + h] = (unsigned int)f2bu(a)
                              | ((unsigned int)f2bu(b) << 16);
        }
        return;
    }

    // Edge-meta pass: bid in [363, 619), 1024 edges per block.
    const int eb = (bid - 363) * 1024;
    #pragma unroll
    for (int r = 0; r < 4; ++r) {
        int i = eb + r * 256 + tid;
        int ent = loadI(nbr_ent, i, i64);
        int rel = loadI(nbr_rel, i, i64);
        float att = loadF(att_raw, i, isB);
        int lo = 0, hi = nIn;   // bucket = #breakpoints <= att
        while (lo < hi) {
            int m = (lo + hi) >> 1;
            if (srt[m] <= att) lo = m + 1; else hi = m;
        }
        unsigned int hiw = (unsigned int)ent
                         | ((unsigned int)rel << 16)
                         | ((unsigned int)lo << 24);
        metaE[i] = make_uint2(__float_as_uint(att), hiw);
    }
}

// ---------------------------------------------------------------------------
// K_B: fused MFMA projection GEMM, LDS-staged. (unchanged)
// ---------------------------------------------------------------------------
#define KB_ENT_BLOCKS (N_ENT_C / 64)   // 625
#define KB_REL_BLOCKS (N_REL_C / 64)   // 4

__global__ void __launch_bounds__(256)
kb_gemm(const void* __restrict__ ent_raw, const void* __restrict__ rel_raw,
        const int* __restrict__ flag,
        const unsigned short* __restrict__ wctEb,
        const unsigned short* __restrict__ wctRb,
        const float* __restrict__ W3b_f, const float* __restrict__ W4b_f,
        unsigned int* __restrict__ entp2, unsigned int* __restrict__ relp2)
{
    const int isB = *flag;
    const int bid = blockIdx.x, tid = threadIdx.x;

    const void* A; const unsigned short* WT; unsigned int* out; int m0, isRel;
    if (bid < KB_ENT_BLOCKS) {
        A = ent_raw; WT = wctEb; out = entp2; m0 = bid * 64; isRel = 0;
    } else {
        A = rel_raw; WT = wctRb; out = relp2;
        m0 = (bid - KB_ENT_BLOCKS) * 64; isRel = 1;
    }

    __shared__ unsigned short As[64][136];   // +8 pad: 272 B row, 16B-aligned

    if (isB) {
        for (int v = tid; v < 1024; v += 256) {      // 1024 short8, coalesced
            int e = v * 8, r = e >> 7, cc = e & 127;
            short8 x = *(const short8*)((const short*)A + m0 * 128 + e);
            *(short8*)&As[r][cc] = x;
        }
    } else {
        for (int v = tid; v < 2048; v += 256) {      // 2048 float4, coalesced
            int e = v * 4, r = e >> 7, cc = e & 127;
            float4 f = *(const float4*)((const float*)A + m0 * 128 + e);
            unsigned int lo = (unsigned int)f2bu(f.x) | ((unsigned int)f2bu(f.y) << 16);
            unsigned int hi = (unsigned int)f2bu(f.z) | ((unsigned int)f2bu(f.w) << 16);
            *(uint2*)&As[r][cc] = make_uint2(lo, hi);
        }
    }
    __syncthreads();

    const int wave = tid >> 6, lane = tid & 63;
    const int quad = lane >> 4, l16 = lane & 15;

    f32x4 acc3[8], acc4[8];
    #pragma unroll
    for (int np = 0; np < 8; ++np) {
        acc3[np] = (f32x4){0.f, 0.f, 0.f, 0.f};
        acc4[np] = (f32x4){0.f, 0.f, 0.f, 0.f};
    }

    #pragma unroll
    for (int kk = 0; kk < 4; ++kk) {
        const int kb = kk * 32 + quad * 8;
        short8 av = *(const short8*)&As[wave * 16 + l16][kb];
        #pragma unroll
        for (int np = 0; np < 8; ++np) {
            const short* bp = (const short*)WT + (np * 16 + l16) * 128 + kb;
            short8 bv3 = *(const short8*)bp;
            short8 bv4 = *(const short8*)(bp + 128 * 128);
            acc3[np] = __builtin_amdgcn_mfma_f32_16x16x32_bf16(av, bv3, acc3[np], 0, 0, 0);
            acc4[np] = __builtin_amdgcn_mfma_f32_16x16x32_bf16(av, bv4, acc4[np], 0, 0, 0);
        }
    }

    #pragma unroll
    for (int np = 0; np < 8; ++np) {
        int h = np * 16 + l16;
        float bias3 = isRel ? W3b_f[h] : 0.0f;
        float bias4 = isRel ? W4b_f[h] : 0.0f;
        #pragma unroll
        for (int r = 0; r < 4; ++r) {
            int m = m0 + wave * 16 + quad * 4 + r;
            unsigned int w = (unsigned int)f2bu(acc3[np][r] + bias3)
                           | ((unsigned int)f2bu(acc4[np][r] + bias4) << 16);
            out[m * 128 + h] = w;
        }
    }
}

// ---------------------------------------------------------------------------
// K_C v3: one WAVE per segment, 2 h-positions per lane.
//  - 256-thr block = 4 waves = 4 segments; ZERO __syncthreads.
//  - all row reads are dwordx2 (uint2): load-instruction count halved.
//  - edge meta comes pre-packed from K_A (one dwordx2/edge, search hoisted).
//  - readlane broadcast of meta -> row bases in SGPRs (scalar addressing).
//  - accumulation order per h identical to v2 -> bitwise-same results.
// ---------------------------------------------------------------------------
__global__ void __launch_bounds__(256)
kc_segment(const uint2* __restrict__ metaE,
           const int* __restrict__ starts,
           const unsigned int* __restrict__ entp2,
           const unsigned int* __restrict__ relp2,
           const unsigned int* __restrict__ ab3p,
           const void* __restrict__ sat_raw,
           const void* __restrict__ s_ids, const void* __restrict__ r_ids,
           const void* __restrict__ ent_raw, const void* __restrict__ rel_raw,
           const float* __restrict__ W1w_f, const float* __restrict__ W1b_f,
           const int* __restrict__ flag, const int* __restrict__ iflag,
           float* __restrict__ outS, float* __restrict__ outA)
{
    const int isB = *flag, i64 = *iflag;
    const int wave = threadIdx.x >> 6, lane = threadIdx.x & 63;
    const int t = blockIdx.x * 4 + wave;          // segment for this wave
    const int h0 = lane * 2;                      // this lane covers h0, h0+1

    const int s = __builtin_amdgcn_readfirstlane(starts[t]);
    const int e = __builtin_amdgcn_readfirstlane(starts[t + 1]);

    float acc3x = 0.0f, acc3y = 0.0f, acc4x = 0.0f, acc4y = 0.0f;

    for (int base = s; base < e; base += 64) {
        const int n = min(64, e - base);
        // stage this chunk's meta into per-lane registers (no LDS, no barrier)
        unsigned int mLo = 0u, mHi = 0u;
        if (lane < n) {
            uint2 mv = metaE[base + lane];
            mLo = mv.x; mHi = mv.y;
        }
        #pragma unroll 4
        for (int ii = 0; ii < n; ++ii) {
            const unsigned int sLo = __builtin_amdgcn_readlane(mLo, ii);
            const unsigned int sHi = __builtin_amdgcn_readlane(mHi, ii);
            const float att = __uint_as_float(sLo);
            const int ent = (int)(sHi & 0xFFFFu);
            const int rel = (int)((sHi >> 16) & 0xFFu);
            const int j   = (int)(sHi >> 24);
            uint2 ew = *(const uint2*)(entp2 + ent * 128 + h0);  // random, L3
            uint2 rw = *(const uint2*)(relp2 + rel * 128 + h0);  // L1/L2-hot
            uint2 aw = *(const uint2*)(ab3p  + j   * 128 + h0);  // L1/L2-hot
            float p3s0 = __uint_as_float(ew.x << 16);
            float p4s0 = __uint_as_float(ew.x & 0xFFFF0000u);
            float p3s1 = __uint_as_float(ew.y << 16);
            float p4s1 = __uint_as_float(ew.y & 0xFFFF0000u);
            float p3r0 = __uint_as_float(rw.x << 16);
            float p4r0 = __uint_as_float(rw.x & 0xFFFF0000u);
            float p3r1 = __uint_as_float(rw.y << 16);
            float p4r1 = __uint_as_float(rw.y & 0xFFFF0000u);
            float a30  = __uint_as_float(aw.x << 16);
            float b30  = __uint_as_float(aw.x & 0xFFFF0000u);
            float a31  = __uint_as_float(aw.y << 16);
            float b31  = __uint_as_float(aw.y & 0xFFFF0000u);
            acc3x += fmaxf(fmaf(att, a30, b30) + p3s0 + p3r0, 0.0f);
            acc3y += fmaxf(fmaf(att, a31, b31) + p3s1 + p3r1, 0.0f);
            acc4x += fmaxf(p4s0 + p4r0, 0.0f);
            acc4y += fmaxf(p4s1 + p4r1, 0.0f);
        }
    }

    const int cnt = e - s;
    const float inv = (cnt > 0) ? (1.0f / (float)cnt) : 1.0f;
    const int b = t / L_SEQ;
    const int sid = loadI(s_ids, b, i64);
    const int rid = loadI(r_ids, b, i64);
    const float se0 = loadF(ent_raw, sid * 128 + h0, isB);
    const float se1 = loadF(ent_raw, sid * 128 + h0 + 1, isB);
    const float sr0 = loadF(rel_raw, rid * 128 + h0, isB);
    const float sr1 = loadF(rel_raw, rid * 128 + h0 + 1, isB);
    const float sa  = loadF(sat_raw, t, isB);
    const float2 w1w = *(const float2*)(W1w_f + h0);
    const float2 w1b = *(const float2*)(W1b_f + h0);
    const float sae0 = fmaxf(fmaf(sa, w1w.x, w1b.x), 0.0f);
    const float sae1 = fmaxf(fmaf(sa, w1w.y, w1b.y), 0.0f);

    const size_t bs = (size_t)t * 384;
    *(float2*)(outS + bs + h0)       = make_float2(se0, se1);
    *(float2*)(outS + bs + 128 + h0) = make_float2(sr0, sr1);
    *(float2*)(outS + bs + 256 + h0) = make_float2(acc4x * inv, acc4y * inv);
    *(float2*)(outA + bs + h0)       = make_float2(sae0, sae1);
    *(float2*)(outA + bs + 128 + h0) = make_float2(se0, se1);
    *(float2*)(outA + bs + 256 + h0) = make_float2(acc3x * inv, acc3y * inv);
}

// ---------------------------------------------------------------------------
extern "C" void kernel_launch(void* const* d_in, const int* in_sizes, int n_in,
                              void* d_out, int out_size, void* d_ws, size_t ws_size,
                              hipStream_t stream)
{
    const void* nbr_ent = d_in[0];
    const void* nbr_rel = d_in[1];
    const void* nbr_att = d_in[2];
    const void* seg_ids = d_in[3];
    const void* self_att = d_in[4];
    const void* s_ids = d_in[5];
    const void* r_ids = d_in[6];
    const void* ent_embeds = d_in[7];
    const void* rel_embeds = d_in[8];
    const void* W1w = d_in[9];
    const void* W1b = d_in[10];
    const void* W3w = d_in[11];
    const void* W3b = d_in[12];
    const void* W4w = d_in[13];
    const void* W4b = d_in[14];

    // workspace carve-up (~23.5 MB)
    char* ws = (char*)d_ws;
    size_t off = 0;
    auto alloc = [&](size_t bytes) -> void* {
        void* p = ws + off;
        off = (off + bytes + 255) & ~(size_t)255;
        return p;
    };
    int*   flag   = (int*)alloc(4);
    int*   iflag  = (int*)alloc(4);
    float* W1w_f  = (float*)alloc(128 * 4);
    float* W1b_f  = (float*)alloc(128 * 4);
    float* W3b_f  = (float*)alloc(128 * 4);
    float* W4b_f  = (float*)alloc(128 * 4);
    int*   starts = (int*)alloc((T_SEG + 1) * 4);
    unsigned short* wctEb = (unsigned short*)alloc(256 * 128 * 2);
    unsigned short* wctRb = (unsigned short*)alloc(256 * 128 * 2);
    unsigned int* ab3p = (unsigned int*)alloc(129 * 128 * 4);
    uint2* metaE = (uint2*)alloc((size_t)E_EDGES * 8);                    // 2 MB
    unsigned int* entp2 = (unsigned int*)alloc((size_t)N_ENT_C * 128 * 4); // 20.48 MB
    unsigned int* relp2 = (unsigned int*)alloc((size_t)N_REL_C * 128 * 4);

    float* outS = (float*)d_out;
    float* outA = outS + (size_t)T_SEG * 384;

    // K_A: all prep (wct tables + ab3p + starts + edge meta + scalars)
    ka_prep<<<619, 256, 0, stream>>>(W3w, W4w, W1w, W1b, W3b, W4b,
                                     seg_ids, nbr_ent, nbr_rel, nbr_att, s_ids,
                                     wctEb, wctRb, ab3p, starts, metaE,
                                     W1w_f, W1b_f, W3b_f, W4b_f,
                                     flag, iflag);

    // K_B: fused entity+relation MFMA projection GEMM (biases folded into rel)
    kb_gemm<<<KB_ENT_BLOCKS + KB_REL_BLOCKS, 256, 0, stream>>>(
        ent_embeds, rel_embeds, flag, wctEb, wctRb, W3b_f, W4b_f, entp2, relp2);

    // K_C: per-segment aggregation + epilogue (1 wave/segment, 4 seg/block)
    kc_segment<<<T_SEG / 4, 256, 0, stream>>>(
        metaE, starts, entp2, relp2, ab3p,
        self_att, s_ids, r_ids, ent_embeds, rel_embeds,
        W1w_f, W1b_f, flag, iflag, outS, outA);
}

// Round 6
// 177.165 us; speedup vs baseline: 1.0705x; 1.0705x over previous
//
#include <hip/hip_runtime.h>
#include <hip/hip_bf16.h>

// Problem constants (from reference)
#define E_EDGES 262144
#define B_SAMP  1024
#define L_SEQ   10
#define T_SEG   (B_SAMP * L_SEQ)   // 10240 segments
#define H_DIM   128
#define N_ENT_C 40000
#define N_REL_C 256

typedef __attribute__((ext_vector_type(8))) short short8;   // 8 bf16 (4 VGPRs)
typedef __attribute__((ext_vector_type(4))) float f32x4;

__device__ __forceinline__ float b2f(__hip_bfloat16 x) { return __bfloat162float(x); }
__device__ __forceinline__ unsigned short f2bu(float x) {
    return __bfloat16_as_ushort(__float2bfloat16(x));
}

// Float load with runtime-detected storage (bf16 vs float32).
__device__ __forceinline__ float loadF(const void* base, int idx, int isB16) {
    if (isB16) return b2f(((const __hip_bfloat16*)base)[idx]);
    return ((const float*)base)[idx];
}
// Integer load with runtime-detected width (int64 vs int32).
__device__ __forceinline__ int loadI(const void* base, int idx, int is64) {
    if (is64) return (int)(((const long long*)base)[idx]);
    return ((const int*)base)[idx];
}

// Per-block dtype detection (cheap, deterministic; no cross-block deps).
__device__ __forceinline__ void detect_dtypes(const void* att_raw,
                                              const void* sid_raw,
                                              int tid, int nthr,
                                              int& isB, int& i64)
{
    __shared__ int cF, cI;
    if (tid == 0) { cF = 0; cI = 0; }
    __syncthreads();
    const unsigned short* pa = (const unsigned short*)att_raw;
    int c = 0;
    for (int i = tid; i < 2048; i += nthr) if (pa[i] <= 0x3F80u) c++;
    if (c) atomicAdd(&cF, c);
    const int* ps = (const int*)sid_raw;
    c = 0;
    for (int i = tid; i < 512; i += nthr) if (ps[2 * i + 1] == 0) c++;
    if (c) atomicAdd(&cI, c);
    __syncthreads();
    isB = (cF >= 1900) ? 1 : 0;
    i64 = (cI >= 256) ? 1 : 0;
}

// ---------------------------------------------------------------------------
// K_A: all prep in one launch, blocks fully independent.
//  bid [0,256):   bf16 weight tables, n-major k-contig for MFMA B-frags.
//  bid [256,321): att piecewise tables ab3p[j][h] = packed {bf16 A3, bf16 B3}.
//  bid [321,362): segment start offsets via lower_bound on sorted seg_ids.
//  bid 362:       global scalar vectors + dtype flags.
//  bid [363,619): edge-meta pass: metaE[i] = uint2{att_f32_bits,
//                 ent u16 | rel u8<<16 | bucket u8<<24}. Hoists the per-edge
//                 breakpoint search out of K_C; K_C stages one uint2/edge.
// ---------------------------------------------------------------------------
__global__ void __launch_bounds__(256)
ka_prep(const void* __restrict__ W3w, const void* __restrict__ W4w,
        const void* __restrict__ W1w, const void* __restrict__ W1b,
        const void* __restrict__ W3b, const void* __restrict__ W4b,
        const void* __restrict__ seg_ids,
        const void* __restrict__ nbr_ent, const void* __restrict__ nbr_rel,
        const void* __restrict__ att_raw, const void* __restrict__ sid_raw,
        unsigned short* __restrict__ wctEb, unsigned short* __restrict__ wctRb,
        unsigned int* __restrict__ ab3p, int* __restrict__ starts,
        uint2* __restrict__ metaE,
        float* __restrict__ W1w_f, float* __restrict__ W1b_f,
        float* __restrict__ W3b_f, float* __restrict__ W4b_f,
        int* __restrict__ flag, int* __restrict__ iflag)
{
    const int bid = blockIdx.x, tid = threadIdx.x;
    int isB, i64;
    detect_dtypes(att_raw, sid_raw, tid, 256, isB, i64);

    if (bid < 256) {
        int gid = bid * 256 + tid;
        if (gid < 32768) {
            int n = gid >> 7, k = gid & 127;
            float v = (n < 128) ? loadF(W3w, n * 384 + 128 + k, isB)
                                : loadF(W4w, (n - 128) * 256 + k, isB);
            wctEb[gid] = f2bu(v);
        } else {
            int j = gid - 32768;
            int n = j >> 7, k = j & 127;
            float v = (n < 128) ? loadF(W3w, n * 384 + 256 + k, isB)
                                : loadF(W4w, (n - 128) * 256 + 128 + k, isB);
            wctRb[j] = f2bu(v);
        }
        return;
    }

    if (bid >= 321 && bid <= 361) {
        // starts blocks: lower_bound on sorted seg_ids
        int t = (bid - 321) * 256 + tid;
        if (t <= T_SEG) {
            int lo = 0, hi = E_EDGES;
            while (lo < hi) {
                int m = (lo + hi) >> 1;
                if (loadI(seg_ids, m, i64) < t) lo = m + 1; else hi = m;
            }
            starts[t] = lo;
        }
        return;
    }

    // Remaining blocks all need the sorted breakpoints: derive locally.
    // thr_k = -b1k/w1k if in (0,1) else sentinel 2.0; rank-sort in LDS.
    __shared__ float w1s[128], b1s[128], srt[128];
    __shared__ int nInS;
    if (tid < 128) {
        float w = loadF(W1w, tid, isB);
        float b = loadF(W1b, tid, isB);
        w1s[tid] = w; b1s[tid] = b;
    }
    __syncthreads();
    if (tid < 128) {
        float w = w1s[tid], b = b1s[tid];
        float t = 2.0f;
        if (w != 0.0f) {
            float tt = -b / w;
            if (tt > 0.0f && tt < 1.0f) t = tt;
        }
        srt[tid] = t;   // temporarily unsorted
    }
    __syncthreads();
    float myt = 0.0f; int rank = 0, n = 0;
    if (tid < 128) {
        myt = srt[tid];
        for (int j = 0; j < 128; ++j) {
            float v = srt[j];
            rank += (v < myt) || (v == myt && j < tid);
            n += (v < 1.5f);
        }
    }
    __syncthreads();
    if (tid < 128) srt[rank] = myt;     // now sorted
    if (tid == 0) nInS = n;
    __syncthreads();
    const int nIn = nInS;

    if (bid == 362) {
        if (tid < 128) {
            W1w_f[tid] = w1s[tid];
            W1b_f[tid] = b1s[tid];
            W3b_f[tid] = loadF(W3b, tid, isB);
            W4b_f[tid] = loadF(W4b, tid, isB);
        }
        if (tid == 0) { *flag = isB; *iflag = i64; }
        return;
    }

    if (bid < 321) {
        // ab3 blocks: j = (bid-256)*2 + (tid>>7), h = tid&127
        const int j = (bid - 256) * 2 + (tid >> 7);
        const int h = tid & 127;
        if (j <= nIn) {
            float left  = (j == 0)   ? 0.0f : srt[j - 1];
            float right = (j == nIn) ? 1.0f : srt[j];
            float mid = 0.5f * (left + right);
            float a = 0.0f, b = 0.0f;
            for (int k = 0; k < 128; ++k) {
                if (fmaf(mid, w1s[k], b1s[k]) > 0.0f) {
                    float w3 = loadF(W3w, h * 384 + k, isB);
                    a = fmaf(w1s[k], w3, a);
                    b = fmaf(b1s[k], w3, b);
                }
            }
            ab3p[j * 128 + h] = (unsigned int)f2bu(a)
                              | ((unsigned int)f2bu(b) << 16);
        }
        return;
    }

    // Edge-meta pass: bid in [363, 619), 1024 edges per block.
    const int eb = (bid - 363) * 1024;
    #pragma unroll
    for (int r = 0; r < 4; ++r) {
        int i = eb + r * 256 + tid;
        int ent = loadI(nbr_ent, i, i64);
        int rel = loadI(nbr_rel, i, i64);
        float att = loadF(att_raw, i, isB);
        int lo = 0, hi = nIn;   // bucket = #breakpoints <= att
        while (lo < hi) {
            int m = (lo + hi) >> 1;
            if (srt[m] <= att) lo = m + 1; else hi = m;
        }
        unsigned int hiw = (unsigned int)ent
                         | ((unsigned int)rel << 16)
                         | ((unsigned int)lo << 24);
        metaE[i] = make_uint2(__float_as_uint(att), hiw);
    }
}

// ---------------------------------------------------------------------------
// K_B v2 (round 6): 32-row tiles, 128-thr blocks (2 waves x 16 rows).
// 2x the resident blocks/CU vs the 64-row version -> staging latency of one
// block overlaps the MFMA+write of neighbors (the 629-block grid was only
// ~2.5 blocks/CU and latency-exposed).
// ---------------------------------------------------------------------------
#define KB_ENT_BLOCKS (N_ENT_C / 32)   // 1250
#define KB_REL_BLOCKS (N_REL_C / 32)   // 8

__global__ void __launch_bounds__(128)
kb_gemm(const void* __restrict__ ent_raw, const void* __restrict__ rel_raw,
        const int* __restrict__ flag,
        const unsigned short* __restrict__ wctEb,
        const unsigned short* __restrict__ wctRb,
        const float* __restrict__ W3b_f, const float* __restrict__ W4b_f,
        unsigned int* __restrict__ entp2, unsigned int* __restrict__ relp2)
{
    const int isB = *flag;
    const int bid = blockIdx.x, tid = threadIdx.x;

    const void* A; const unsigned short* WT; unsigned int* out; int m0, isRel;
    if (bid < KB_ENT_BLOCKS) {
        A = ent_raw; WT = wctEb; out = entp2; m0 = bid * 32; isRel = 0;
    } else {
        A = rel_raw; WT = wctRb; out = relp2;
        m0 = (bid - KB_ENT_BLOCKS) * 32; isRel = 1;
    }

    __shared__ unsigned short As[32][136];   // +8 pad: 272 B row, 16B-aligned

    if (isB) {
        for (int v = tid; v < 512; v += 128) {       // 512 short8, coalesced
            int e = v * 8, r = e >> 7, cc = e & 127;
            short8 x = *(const short8*)((const short*)A + m0 * 128 + e);
            *(short8*)&As[r][cc] = x;
        }
    } else {
        for (int v = tid; v < 1024; v += 128) {      // 1024 float4, coalesced
            int e = v * 4, r = e >> 7, cc = e & 127;
            float4 f = *(const float4*)((const float*)A + m0 * 128 + e);
            unsigned int lo = (unsigned int)f2bu(f.x) | ((unsigned int)f2bu(f.y) << 16);
            unsigned int hi = (unsigned int)f2bu(f.z) | ((unsigned int)f2bu(f.w) << 16);
            *(uint2*)&As[r][cc] = make_uint2(lo, hi);
        }
    }
    __syncthreads();

    const int wave = tid >> 6, lane = tid & 63;
    const int quad = lane >> 4, l16 = lane & 15;

    f32x4 acc3[8], acc4[8];
    #pragma unroll
    for (int np = 0; np < 8; ++np) {
        acc3[np] = (f32x4){0.f, 0.f, 0.f, 0.f};
        acc4[np] = (f32x4){0.f, 0.f, 0.f, 0.f};
    }

    #pragma unroll
    for (int kk = 0; kk < 4; ++kk) {
        const int kb = kk * 32 + quad * 8;
        short8 av = *(const short8*)&As[wave * 16 + l16][kb];
        #pragma unroll
        for (int np = 0; np < 8; ++np) {
            const short* bp = (const short*)WT + (np * 16 + l16) * 128 + kb;
            short8 bv3 = *(const short8*)bp;
            short8 bv4 = *(const short8*)(bp + 128 * 128);
            acc3[np] = __builtin_amdgcn_mfma_f32_16x16x32_bf16(av, bv3, acc3[np], 0, 0, 0);
            acc4[np] = __builtin_amdgcn_mfma_f32_16x16x32_bf16(av, bv4, acc4[np], 0, 0, 0);
        }
    }

    #pragma unroll
    for (int np = 0; np < 8; ++np) {
        int h = np * 16 + l16;
        float bias3 = isRel ? W3b_f[h] : 0.0f;
        float bias4 = isRel ? W4b_f[h] : 0.0f;
        #pragma unroll
        for (int r = 0; r < 4; ++r) {
            int m = m0 + wave * 16 + quad * 4 + r;
            unsigned int w = (unsigned int)f2bu(acc3[np][r] + bias3)
                           | ((unsigned int)f2bu(acc4[np][r] + bias4) << 16);
            out[m * 128 + h] = w;
        }
    }
}

// ---------------------------------------------------------------------------
// K_C v5 (round 6): revert to the verified v2 structure (1 block/segment,
// 128 thr, LDS edge staging + ds_read broadcast, unroll 8 -> 24 outstanding
// gathers/wave) with the metaE precompute kept from v3 (staging is one uint2
// per edge, no in-kernel search). Accumulation order per h identical to the
// 179.18us round-3 kernel -> bitwise-same results.
// ---------------------------------------------------------------------------
__global__ void __launch_bounds__(128)
kc_segment(const uint2* __restrict__ metaE,
           const int* __restrict__ starts,
           const unsigned int* __restrict__ entp2,
           const unsigned int* __restrict__ relp2,
           const unsigned int* __restrict__ ab3p,
           const void* __restrict__ sat_raw,
           const void* __restrict__ s_ids, const void* __restrict__ r_ids,
           const void* __restrict__ ent_raw, const void* __restrict__ rel_raw,
           const float* __restrict__ W1w_f, const float* __restrict__ W1b_f,
           const int* __restrict__ flag, const int* __restrict__ iflag,
           float* __restrict__ outS, float* __restrict__ outA)
{
    const int t = blockIdx.x, h = threadIdx.x;
    const int isB = *flag, i64 = *iflag;
    const int s = starts[t], e = starts[t + 1];

    __shared__ uint2 eS[128];

    float acc3 = 0.0f, acc4 = 0.0f;

    for (int base = s; base < e; base += 128) {
        const int n = min(128, e - base);
        __syncthreads();
        if (h < n) eS[h] = metaE[base + h];
        __syncthreads();
        #pragma unroll 8
        for (int ii = 0; ii < n; ++ii) {
            uint2 q = eS[ii];                         // ds_read_b64 broadcast
            float att = __uint_as_float(q.x);
            int ent = (int)(q.y & 0xFFFFu);
            int rel = (int)((q.y >> 16) & 0xFFu);
            int j   = (int)(q.y >> 24);
            unsigned int ew = entp2[ent * 128 + h];   // random L3 gather
            unsigned int rw = relp2[rel * 128 + h];   // L2-hot (+biases)
            unsigned int aw = ab3p[j * 128 + h];      // L2-hot, bf16-packed
            float p3s = __uint_as_float(ew << 16);
            float p4s = __uint_as_float(ew & 0xFFFF0000u);
            float p3r = __uint_as_float(rw << 16);
            float p4r = __uint_as_float(rw & 0xFFFF0000u);
            float a3  = __uint_as_float(aw << 16);
            float b3  = __uint_as_float(aw & 0xFFFF0000u);
            acc3 += fmaxf(fmaf(att, a3, b3) + p3s + p3r, 0.0f);
            acc4 += fmaxf(p4s + p4r, 0.0f);
        }
    }

    const int cnt = e - s;
    const float inv = (cnt > 0) ? (1.0f / (float)cnt) : 1.0f;
    const int b = t / L_SEQ;
    const int sid = loadI(s_ids, b, i64);
    const int rid = loadI(r_ids, b, i64);
    const float se = loadF(ent_raw, sid * 128 + h, isB);
    const float sr = loadF(rel_raw, rid * 128 + h, isB);
    const float sa = loadF(sat_raw, t, isB);
    const float sae = fmaxf(fmaf(sa, W1w_f[h], W1b_f[h]), 0.0f);

    const size_t bs = (size_t)t * 384;
    outS[bs + h]       = se;
    outS[bs + 128 + h] = sr;
    outS[bs + 256 + h] = acc4 * inv;
    outA[bs + h]       = sae;
    outA[bs + 128 + h] = se;
    outA[bs + 256 + h] = acc3 * inv;
}

// ---------------------------------------------------------------------------
extern "C" void kernel_launch(void* const* d_in, const int* in_sizes, int n_in,
                              void* d_out, int out_size, void* d_ws, size_t ws_size,
                              hipStream_t stream)
{
    const void* nbr_ent = d_in[0];
    const void* nbr_rel = d_in[1];
    const void* nbr_att = d_in[2];
    const void* seg_ids = d_in[3];
    const void* self_att = d_in[4];
    const void* s_ids = d_in[5];
    const void* r_ids = d_in[6];
    const void* ent_embeds = d_in[7];
    const void* rel_embeds = d_in[8];
    const void* W1w = d_in[9];
    const void* W1b = d_in[10];
    const void* W3w = d_in[11];
    const void* W3b = d_in[12];
    const void* W4w = d_in[13];
    const void* W4b = d_in[14];

    // workspace carve-up (~23.5 MB)
    char* ws = (char*)d_ws;
    size_t off = 0;
    auto alloc = [&](size_t bytes) -> void* {
        void* p = ws + off;
        off = (off + bytes + 255) & ~(size_t)255;
        return p;
    };
    int*   flag   = (int*)alloc(4);
    int*   iflag  = (int*)alloc(4);
    float* W1w_f  = (float*)alloc(128 * 4);
    float* W1b_f  = (float*)alloc(128 * 4);
    float* W3b_f  = (float*)alloc(128 * 4);
    float* W4b_f  = (float*)alloc(128 * 4);
    int*   starts = (int*)alloc((T_SEG + 1) * 4);
    unsigned short* wctEb = (unsigned short*)alloc(256 * 128 * 2);
    unsigned short* wctRb = (unsigned short*)alloc(256 * 128 * 2);
    unsigned int* ab3p = (unsigned int*)alloc(129 * 128 * 4);
    uint2* metaE = (uint2*)alloc((size_t)E_EDGES * 8);                    // 2 MB
    unsigned int* entp2 = (unsigned int*)alloc((size_t)N_ENT_C * 128 * 4); // 20.48 MB
    unsigned int* relp2 = (unsigned int*)alloc((size_t)N_REL_C * 128 * 4);

    float* outS = (float*)d_out;
    float* outA = outS + (size_t)T_SEG * 384;

    // K_A: all prep (wct tables + ab3p + starts + edge meta + scalars)
    ka_prep<<<619, 256, 0, stream>>>(W3w, W4w, W1w, W1b, W3b, W4b,
                                     seg_ids, nbr_ent, nbr_rel, nbr_att, s_ids,
                                     wctEb, wctRb, ab3p, starts, metaE,
                                     W1w_f, W1b_f, W3b_f, W4b_f,
                                     flag, iflag);

    // K_B: fused entity+relation MFMA projection GEMM (biases folded into rel)
    kb_gemm<<<KB_ENT_BLOCKS + KB_REL_BLOCKS, 128, 0, stream>>>(
        ent_embeds, rel_embeds, flag, wctEb, wctRb, W3b_f, W4b_f, entp2, relp2);

    // K_C: per-segment aggregation + epilogue (1 block/segment, 128 thr)
    kc_segment<<<T_SEG, 128, 0, stream>>>(
        metaE, starts, entp2, relp2, ab3p,
        self_att, s_ids, r_ids, ent_embeds, rel_embeds,
        W1w_f, W1b_f, flag, iflag, outS, outA);
}